// Round 4
// baseline (273.874 us; speedup 1.0000x reference)
//
#include <hip/hip_runtime.h>

typedef unsigned short u16;
typedef __attribute__((ext_vector_type(8))) short short8;
typedef __attribute__((ext_vector_type(4))) float f32x4;

#define D_TOT 2048
#define M_TOT 64
#define H_TOT 128
#define B_TOT 256
#define NGRP  128      /* reduction groups: each = 2 d-slices = 16 d */
#define XB    131072   /* D_TOT*M_TOT : x row stride per b */
#define W1M   262144   /* H_TOT*D_TOT : w1 stride per m */

__device__ __forceinline__ u16 f2bf(float f) {
  unsigned u = __builtin_bit_cast(unsigned, f);
  u = (u + 0x7fffu + ((u >> 16) & 1u)) >> 16;   // round-to-nearest-even
  return (u16)u;
}
__device__ __forceinline__ float bf2f(u16 v) {
  unsigned u = ((unsigned)v) << 16;
  return __builtin_bit_cast(float, u);
}

// ---------------------------------------------------------------------------
// phase 0: c[h] = b2[h] + sum_d b1[h,d]*w2[h,d]      grid 128 x 256
// ---------------------------------------------------------------------------
__global__ __launch_bounds__(256)
void nlm_p0(const float* __restrict__ b1, const float* __restrict__ w2,
            const float* __restrict__ b2, float* __restrict__ ch) {
  const int h = blockIdx.x, t = threadIdx.x;
  const float4* pb = (const float4*)(b1 + (size_t)h * D_TOT);
  const float4* pw = (const float4*)(w2 + (size_t)h * D_TOT);
  float s = 0.f;
  for (int i = t; i < D_TOT / 4; i += 256) {
    float4 a = pb[i], w = pw[i];
    s += a.x * w.x + a.y * w.y + a.z * w.z + a.w * w.w;
  }
  __shared__ float red[256];
  red[t] = s;
  __syncthreads();
  for (int off = 128; off > 0; off >>= 1) {
    if (t < off) red[t] += red[t + off];
    __syncthreads();
  }
  if (t == 0) ch[h] = red[0] + b2[h];
}

// ---------------------------------------------------------------------------
// pw: pre-pack B'[dg][h][m] = bf16( w1[m][h][dg] * w2[h][dg] ),  dg = 0..2047.
// Reads w1 in FULL 128-B d-runs (exact 67 MB), writes 33.5 MB streaming.
// grid 512 = 64 d-blocks (32 d) x 8 h-blocks (16 h), block 256.
// ---------------------------------------------------------------------------
__global__ __launch_bounds__(256)
void nlm_pw(const float* __restrict__ w1, const float* __restrict__ w2,
            u16* __restrict__ Bp) {
  const int gq  = blockIdx.x & 63;
  const int hb  = blockIdx.x >> 6;
  const int dq0 = gq * 32;
  const int t   = threadIdx.x;
  __shared__ u16 tile[32 * 16 * 64];  // [dc][h_l][m] = 64 KB

  // 1024 tasks: tau = h_l*64 + m  (wave-uniform h -> w2 loads broadcast)
#pragma unroll
  for (int rep = 0; rep < 4; ++rep) {
    const int tau = rep * 256 + t;
    const int h_l = tau >> 6, m = tau & 63;
    const int h   = hb * 16 + h_l;
    const float* w1p = w1 + (size_t)m * W1M + (size_t)h * D_TOT + dq0;
    const float* w2p = w2 + (size_t)h * D_TOT + dq0;
    u16* dst = tile + h_l * 64 + m;   // + dc*1024
#pragma unroll
    for (int q = 0; q < 8; ++q) {      // 8 x float4 = the full 128-B line
      float4 a = *(const float4*)(w1p + q * 4);
      float4 s = *(const float4*)(w2p + q * 4);
      dst[(q * 4 + 0) * 1024] = f2bf(a.x * s.x);
      dst[(q * 4 + 1) * 1024] = f2bf(a.y * s.y);
      dst[(q * 4 + 2) * 1024] = f2bf(a.z * s.z);
      dst[(q * 4 + 3) * 1024] = f2bf(a.w * s.w);
    }
  }
  __syncthreads();
  // write out 32 contiguous 2-KB segments (one per dc)
#pragma unroll 4
  for (int dc = 0; dc < 32; ++dc) {
    const int dg = dq0 + dc;
    u16* out = Bp + ((size_t)dg * H_TOT + hb * 16) * 64 + t * 4;
    *(ushort4*)out = *(const ushort4*)(tile + dc * 1024 + t * 4);
  }
}

// ---------------------------------------------------------------------------
// phase 1: partial[b][G][h] = sum over 16 d (G-group) of x * B'.
// chunk = single d, all 64 m: A-stage = full 256-B x rows, exact-once.
// grid 512 = 4 bq x 128 G; blockIdx%8 = G%8 -> the 4 bq-sharers of B'[G]
// land on one XCD (all 512 WGs co-resident at 2 WG/CU).
// block 512 = 8 waves as 2(wm) x 4(wn); per-wave tile 32b x 32h.
// Register prefetch: chunk c+1's global loads issue before chunk c's MFMAs.
// ---------------------------------------------------------------------------
__global__ __launch_bounds__(512, 4)
void nlm_p1(const float* __restrict__ x, const u16* __restrict__ Bp,
            u16* __restrict__ partial) {
  __shared__ __align__(16) u16 As[64 * 72];    // row b_l, 64 m + 8 pad
  __shared__ __align__(16) u16 Bs[128 * 72];   // row h,   64 m + 8 pad

  const int tid  = threadIdx.x;
  const int G    = blockIdx.x & 127;
  const int bq   = blockIdx.x >> 7;
  const int dg0  = G * 16;
  const int lane = tid & 63, wave = tid >> 6;
  const int wm   = wave >> 2;         // 0..1
  const int wn   = wave & 3;          // 0..3
  const int quad = lane >> 4, l16 = lane & 15;

  // A staging: thread -> (b_l = tid>>3, part = tid&7): 32 B of one x row
  const int a_bl = tid >> 3, a_p = tid & 7;
  const float* xrow = x + (size_t)(bq * 64 + a_bl) * XB
                        + (size_t)dg0 * M_TOT + a_p * 8;
  // B staging: thread -> (h = tid>>2, qp = tid&3): 32 B of B' chunk
  const int b_h = tid >> 2, b_qp = tid & 3;
  const u16* bsrc = Bp + ((size_t)dg0 * H_TOT + b_h) * 64 + b_qp * 16;

  f32x4 acc[2][2];
#pragma unroll
  for (int i = 0; i < 2; ++i)
#pragma unroll
    for (int j = 0; j < 2; ++j) acc[i][j] = (f32x4){0.f, 0.f, 0.f, 0.f};

  float4 xv0, xv1; short8 bv0, bv1;
  {
    const float* xp = xrow;
    xv0 = *(const float4*)(xp);
    xv1 = *(const float4*)(xp + 4);
    bv0 = *(const short8*)(bsrc);
    bv1 = *(const short8*)(bsrc + 8);
  }

  for (int c = 0; c < 16; ++c) {
    { // ---- LDS write from prefetched regs
      short8 av;
      av[0] = (short)f2bf(xv0.x); av[1] = (short)f2bf(xv0.y);
      av[2] = (short)f2bf(xv0.z); av[3] = (short)f2bf(xv0.w);
      av[4] = (short)f2bf(xv1.x); av[5] = (short)f2bf(xv1.y);
      av[6] = (short)f2bf(xv1.z); av[7] = (short)f2bf(xv1.w);
      *(short8*)(As + a_bl * 72 + a_p * 8) = av;
      *(short8*)(Bs + b_h * 72 + b_qp * 16)     = bv0;
      *(short8*)(Bs + b_h * 72 + b_qp * 16 + 8) = bv1;
    }
    __syncthreads();
    if (c < 15) { // ---- prefetch next chunk (drains at next LDS write)
      const float* xp = xrow + (c + 1) * M_TOT;
      xv0 = *(const float4*)(xp);
      xv1 = *(const float4*)(xp + 4);
      const u16* bp = bsrc + (size_t)(c + 1) * (H_TOT * 64);
      bv0 = *(const short8*)(bp);
      bv1 = *(const short8*)(bp + 8);
    }
#pragma unroll
    for (int s = 0; s < 2; ++s) {
      short8 af[2], bf[2];
#pragma unroll
      for (int i = 0; i < 2; ++i)
        af[i] = *(const short8*)(As + (wm * 32 + i * 16 + l16) * 72 + s * 32 + quad * 8);
#pragma unroll
      for (int j = 0; j < 2; ++j)
        bf[j] = *(const short8*)(Bs + (wn * 32 + j * 16 + l16) * 72 + s * 32 + quad * 8);
#pragma unroll
      for (int i = 0; i < 2; ++i)
#pragma unroll
        for (int j = 0; j < 2; ++j)
          acc[i][j] = __builtin_amdgcn_mfma_f32_16x16x32_bf16(af[i], bf[j], acc[i][j], 0, 0, 0);
    }
    __syncthreads();
  }

  // ---- epilogue: bf16 partials [b][G][h]; wn-waves cover full 256-B h-rows
#pragma unroll
  for (int i = 0; i < 2; ++i)
#pragma unroll
    for (int j = 0; j < 2; ++j) {
      const int hcol = wn * 32 + j * 16 + l16;
#pragma unroll
      for (int r = 0; r < 4; ++r) {
        const int brow = bq * 64 + wm * 32 + i * 16 + quad * 4 + r;
        partial[((size_t)brow * NGRP + G) * H_TOT + hcol] = f2bf(acc[i][j][r]);
      }
    }
}

// ---------------------------------------------------------------------------
// phase 2: out[b,h] = sum_G partial[b][G][h] + c[h]     grid 256 x 256
// each block streams its 32 KB of partial fully contiguously
// ---------------------------------------------------------------------------
__global__ __launch_bounds__(256)
void nlm_p2(const u16* __restrict__ partial, const float* __restrict__ ch,
            float* __restrict__ out) {
  const int b = blockIdx.x, t = threadIdx.x;
  const int h2   = t & 63;    // ushort2 column: h = 2*h2, 2*h2+1
  const int qtr  = t >> 6;    // 0..3 : G range of 32
  const u16* base = partial + ((size_t)b * NGRP + qtr * 32) * H_TOT + 2 * h2;
  float s0 = 0.f, s1 = 0.f;
#pragma unroll 8
  for (int gg = 0; gg < 32; ++gg) {
    unsigned v = __builtin_nontemporal_load((const unsigned*)(base + (size_t)gg * H_TOT));
    s0 += bf2f((u16)(v & 0xffffu));
    s1 += bf2f((u16)(v >> 16));
  }
  __shared__ float red0[256], red1[256];
  red0[t] = s0;
  red1[t] = s1;
  __syncthreads();
  if (t < 64) {
    float a0 = red0[t] + red0[t + 64] + red0[t + 128] + red0[t + 192];
    float a1 = red1[t] + red1[t + 64] + red1[t + 128] + red1[t + 192];
    out[(size_t)b * H_TOT + 2 * t]     = a0 + ch[2 * t];
    out[(size_t)b * H_TOT + 2 * t + 1] = a1 + ch[2 * t + 1];
  }
}

// ---------------------------------------------------------------------------
extern "C" void kernel_launch(void* const* d_in, const int* in_sizes, int n_in,
                              void* d_out, int out_size, void* d_ws, size_t ws_size,
                              hipStream_t stream) {
  const float* x  = (const float*)d_in[0];
  const float* w1 = (const float*)d_in[1];
  const float* b1 = (const float*)d_in[2];
  const float* w2 = (const float*)d_in[3];
  const float* b2 = (const float*)d_in[4];
  float* out = (float*)d_out;

  // ws: partial 8.39 MB | B' 33.55 MB | ch 512 B   (needs ~42 MB)
  u16*   partial = (u16*)d_ws;
  u16*   Bp      = (u16*)((char*)d_ws + (size_t)B_TOT * NGRP * H_TOT * sizeof(u16));
  float* ch      = (float*)((char*)d_ws + (size_t)B_TOT * NGRP * H_TOT * sizeof(u16)
                                        + (size_t)D_TOT * H_TOT * 64 * sizeof(u16));

  nlm_p0<<<dim3(128),  dim3(256), 0, stream>>>(b1, w2, b2, ch);
  nlm_pw<<<dim3(512),  dim3(256), 0, stream>>>(w1, w2, Bp);
  nlm_p1<<<dim3(512),  dim3(512), 0, stream>>>(x, Bp, partial);
  nlm_p2<<<dim3(256),  dim3(256), 0, stream>>>(partial, ch, out);
}

// Round 5
// 267.598 us; speedup vs baseline: 1.0235x; 1.0235x over previous
//
#include <hip/hip_runtime.h>

typedef unsigned short u16;
typedef __attribute__((ext_vector_type(8))) short short8;
typedef __attribute__((ext_vector_type(4))) float f32x4;

#define D_TOT 2048
#define M_TOT 64
#define H_TOT 128
#define B_TOT 256
#define NG    256      /* number of d-slices (each 8 d's) */
#define XB    131072   /* D_TOT*M_TOT : x row stride per b */
#define W1M   262144   /* H_TOT*D_TOT : w1 stride per m */

__device__ __forceinline__ u16 f2bf(float f) {
  unsigned u = __builtin_bit_cast(unsigned, f);
  u = (u + 0x7fffu + ((u >> 16) & 1u)) >> 16;   // round-to-nearest-even
  return (u16)u;
}
__device__ __forceinline__ float bf2f(u16 v) {
  unsigned u = ((unsigned)v) << 16;
  return __builtin_bit_cast(float, u);
}

// ---------------------------------------------------------------------------
// phase 0: c[h] = b2[h] + sum_d b1[h,d]*w2[h,d]      grid 128 x 256
// ---------------------------------------------------------------------------
__global__ __launch_bounds__(256)
void nlm_p0(const float* __restrict__ b1, const float* __restrict__ w2,
            const float* __restrict__ b2, float* __restrict__ ch) {
  const int h = blockIdx.x, t = threadIdx.x;
  const float4* pb = (const float4*)(b1 + (size_t)h * D_TOT);
  const float4* pw = (const float4*)(w2 + (size_t)h * D_TOT);
  float s = 0.f;
  for (int i = t; i < D_TOT / 4; i += 256) {
    float4 a = pb[i], w = pw[i];
    s += a.x * w.x + a.y * w.y + a.z * w.z + a.w * w.w;
  }
  __shared__ float red[256];
  red[t] = s;
  __syncthreads();
  for (int off = 128; off > 0; off >>= 1) {
    if (t < off) red[t] += red[t + off];
    __syncthreads();
  }
  if (t == 0) ch[h] = red[0] + b2[h];
}

// ---------------------------------------------------------------------------
// pw: pre-pack B'[dg][h][m] = bf16( w1[m][h][dg] * w2[h][dg] ),  dg = 0..2047.
// Reads w1 in FULL 128-B d-runs (exact 67 MB), writes 33.5 MB streaming.
// grid 512 = 64 d-blocks (32 d) x 8 h-blocks (16 h), block 256.
// ---------------------------------------------------------------------------
__global__ __launch_bounds__(256)
void nlm_pw(const float* __restrict__ w1, const float* __restrict__ w2,
            u16* __restrict__ Bp) {
  const int gq  = blockIdx.x & 63;
  const int hb  = blockIdx.x >> 6;
  const int dq0 = gq * 32;
  const int t   = threadIdx.x;
  __shared__ u16 tile[32 * 16 * 64];  // [dc][h_l][m] = 64 KB

  // 1024 tasks: tau = h_l*64 + m  (wave-uniform h -> w2 loads broadcast)
#pragma unroll
  for (int rep = 0; rep < 4; ++rep) {
    const int tau = rep * 256 + t;
    const int h_l = tau >> 6, m = tau & 63;
    const int h   = hb * 16 + h_l;
    const float* w1p = w1 + (size_t)m * W1M + (size_t)h * D_TOT + dq0;
    const float* w2p = w2 + (size_t)h * D_TOT + dq0;
    u16* dst = tile + h_l * 64 + m;   // + dc*1024
#pragma unroll
    for (int q = 0; q < 8; ++q) {      // 8 x float4 = the full 128-B line
      float4 a = *(const float4*)(w1p + q * 4);
      float4 s = *(const float4*)(w2p + q * 4);
      dst[(q * 4 + 0) * 1024] = f2bf(a.x * s.x);
      dst[(q * 4 + 1) * 1024] = f2bf(a.y * s.y);
      dst[(q * 4 + 2) * 1024] = f2bf(a.z * s.z);
      dst[(q * 4 + 3) * 1024] = f2bf(a.w * s.w);
    }
  }
  __syncthreads();
  // write out 32 contiguous 2-KB segments (one per dc)
#pragma unroll 4
  for (int dc = 0; dc < 32; ++dc) {
    const int dg = dq0 + dc;
    u16* out = Bp + ((size_t)dg * H_TOT + hb * 16) * 64 + t * 4;
    *(ushort4*)out = *(const ushort4*)(tile + dc * 1024 + t * 4);
  }
}

// ---------------------------------------------------------------------------
// phase 1: partial[b][g][h] = sum over 8 d (slice g) of x * B'.
// chunk = single d, all 64 m: A-stage = full 256-B x rows, exact-once.
// grid 1024 = 4 bq x 256 g; blockIdx%8 = g%8 -> 4 bq-sharers of B'[g] land
// on one XCD; 1024 WGs = 4 WG/CU (32 waves/CU, full occupancy).
// block 512 = 8 waves as 2(wm) x 4(wn); per-wave tile 32b x 32h.
// Register prefetch: chunk c+1's global loads issue before chunk c's MFMAs
// and drain only at the next LDS write.
// ---------------------------------------------------------------------------
__global__ __launch_bounds__(512, 4)
void nlm_p1(const float* __restrict__ x, const u16* __restrict__ Bp,
            u16* __restrict__ partial) {
  __shared__ __align__(16) u16 As[64 * 72];    // row b_l, 64 m + 8 pad
  __shared__ __align__(16) u16 Bs[128 * 72];   // row h,   64 m + 8 pad

  const int tid  = threadIdx.x;
  const int g    = blockIdx.x & 255;
  const int bq   = blockIdx.x >> 8;
  const int d0   = g * 8;
  const int lane = tid & 63, wave = tid >> 6;
  const int wm   = wave >> 2;         // 0..1
  const int wn   = wave & 3;          // 0..3
  const int quad = lane >> 4, l16 = lane & 15;

  // A staging: thread -> (b_l = tid>>3, part = tid&7): 32 B of one x row
  const int a_bl = tid >> 3, a_p = tid & 7;
  const float* xrow = x + (size_t)(bq * 64 + a_bl) * XB
                        + (size_t)d0 * M_TOT + a_p * 8;
  // B staging: thread -> (h = tid>>2, qp = tid&3): 32 B of B' chunk
  const int b_h = tid >> 2, b_qp = tid & 3;
  const u16* bsrc = Bp + ((size_t)d0 * H_TOT + b_h) * 64 + b_qp * 16;

  f32x4 acc[2][2];
#pragma unroll
  for (int i = 0; i < 2; ++i)
#pragma unroll
    for (int j = 0; j < 2; ++j) acc[i][j] = (f32x4){0.f, 0.f, 0.f, 0.f};

  float4 xv0, xv1; short8 bv0, bv1;
  {
    xv0 = *(const float4*)(xrow);
    xv1 = *(const float4*)(xrow + 4);
    bv0 = *(const short8*)(bsrc);
    bv1 = *(const short8*)(bsrc + 8);
  }

  for (int c = 0; c < 8; ++c) {
    { // ---- LDS write from prefetched regs
      short8 av;
      av[0] = (short)f2bf(xv0.x); av[1] = (short)f2bf(xv0.y);
      av[2] = (short)f2bf(xv0.z); av[3] = (short)f2bf(xv0.w);
      av[4] = (short)f2bf(xv1.x); av[5] = (short)f2bf(xv1.y);
      av[6] = (short)f2bf(xv1.z); av[7] = (short)f2bf(xv1.w);
      *(short8*)(As + a_bl * 72 + a_p * 8) = av;
      *(short8*)(Bs + b_h * 72 + b_qp * 16)     = bv0;
      *(short8*)(Bs + b_h * 72 + b_qp * 16 + 8) = bv1;
    }
    __syncthreads();
    if (c < 7) { // ---- prefetch next chunk
      const float* xp = xrow + (c + 1) * M_TOT;
      xv0 = *(const float4*)(xp);
      xv1 = *(const float4*)(xp + 4);
      const u16* bp = bsrc + (size_t)(c + 1) * (H_TOT * 64);
      bv0 = *(const short8*)(bp);
      bv1 = *(const short8*)(bp + 8);
    }
#pragma unroll
    for (int s = 0; s < 2; ++s) {
      short8 af[2], bf[2];
#pragma unroll
      for (int i = 0; i < 2; ++i)
        af[i] = *(const short8*)(As + (wm * 32 + i * 16 + l16) * 72 + s * 32 + quad * 8);
#pragma unroll
      for (int j = 0; j < 2; ++j)
        bf[j] = *(const short8*)(Bs + (wn * 32 + j * 16 + l16) * 72 + s * 32 + quad * 8);
#pragma unroll
      for (int i = 0; i < 2; ++i)
#pragma unroll
        for (int j = 0; j < 2; ++j)
          acc[i][j] = __builtin_amdgcn_mfma_f32_16x16x32_bf16(af[i], bf[j], acc[i][j], 0, 0, 0);
    }
    __syncthreads();
  }

  // ---- epilogue: bf16 partials [b][g][h]; wn-waves cover full 256-B h-rows
#pragma unroll
  for (int i = 0; i < 2; ++i)
#pragma unroll
    for (int j = 0; j < 2; ++j) {
      const int hcol = wn * 32 + j * 16 + l16;
#pragma unroll
      for (int r = 0; r < 4; ++r) {
        const int brow = bq * 64 + wm * 32 + i * 16 + quad * 4 + r;
        partial[((size_t)brow * NG + g) * H_TOT + hcol] = f2bf(acc[i][j][r]);
      }
    }
}

// ---------------------------------------------------------------------------
// phase 2: out[b,h] = sum_g partial[b][g][h] + c[h]     grid 256 x 256
// each block streams its 64 KB of partial fully contiguously
// ---------------------------------------------------------------------------
__global__ __launch_bounds__(256)
void nlm_p2(const u16* __restrict__ partial, const float* __restrict__ ch,
            float* __restrict__ out) {
  const int b = blockIdx.x, t = threadIdx.x;
  const int h2   = t & 63;    // ushort2 column: h = 2*h2, 2*h2+1
  const int qtr  = t >> 6;    // 0..3 : g range of 64
  const u16* base = partial + ((size_t)b * NG + qtr * 64) * H_TOT + 2 * h2;
  float s0 = 0.f, s1 = 0.f;
#pragma unroll 8
  for (int gg = 0; gg < 64; ++gg) {
    unsigned v = __builtin_nontemporal_load((const unsigned*)(base + (size_t)gg * H_TOT));
    s0 += bf2f((u16)(v & 0xffffu));
    s1 += bf2f((u16)(v >> 16));
  }
  __shared__ float red0[256], red1[256];
  red0[t] = s0;
  red1[t] = s1;
  __syncthreads();
  if (t < 64) {
    float a0 = red0[t] + red0[t + 64] + red0[t + 128] + red0[t + 192];
    float a1 = red1[t] + red1[t + 64] + red1[t + 128] + red1[t + 192];
    out[(size_t)b * H_TOT + 2 * t]     = a0 + ch[2 * t];
    out[(size_t)b * H_TOT + 2 * t + 1] = a1 + ch[2 * t + 1];
  }
}

// ---------------------------------------------------------------------------
extern "C" void kernel_launch(void* const* d_in, const int* in_sizes, int n_in,
                              void* d_out, int out_size, void* d_ws, size_t ws_size,
                              hipStream_t stream) {
  const float* x  = (const float*)d_in[0];
  const float* w1 = (const float*)d_in[1];
  const float* b1 = (const float*)d_in[2];
  const float* w2 = (const float*)d_in[3];
  const float* b2 = (const float*)d_in[4];
  float* out = (float*)d_out;

  // ws: partial 16.78 MB | B' 33.55 MB | ch 512 B   (needs ~50.4 MB)
  u16*   partial = (u16*)d_ws;
  u16*   Bp      = (u16*)((char*)d_ws + (size_t)B_TOT * NG * H_TOT * sizeof(u16));
  float* ch      = (float*)((char*)d_ws + (size_t)B_TOT * NG * H_TOT * sizeof(u16)
                                        + (size_t)D_TOT * H_TOT * 64 * sizeof(u16));

  nlm_p0<<<dim3(128),  dim3(256), 0, stream>>>(b1, w2, b2, ch);
  nlm_pw<<<dim3(512),  dim3(256), 0, stream>>>(w1, w2, Bp);
  nlm_p1<<<dim3(1024), dim3(512), 0, stream>>>(x, Bp, partial);
  nlm_p2<<<dim3(256),  dim3(256), 0, stream>>>(partial, ch, out);
}